// Round 3
// baseline (855.362 us; speedup 1.0000x reference)
//
#include <hip/hip_runtime.h>
#include <hip/hip_bf16.h>
#include <math.h>

// Problem constants (from reference)
#define Bq   4
#define Tq   512
#define Hq   512
#define Vq   32000
#define Sq   512
#define SDVq 300
#define TDVq 512
#define ROWS (Bq * Tq)            // 2048
#define OUTW (Vq + SDVq + TDVq)   // 32812
#define NBLK 250                  // n-tiles of 128 in Vq

typedef __bf16 bf16x8 __attribute__((ext_vector_type(8)));
typedef float  fx4    __attribute__((ext_vector_type(4)));

// -------------------------------------------------------------------------
// K1: p = softmax(h @ Wp + bp) per row; one wave per row.
__global__ void compute_p(const float* __restrict__ hiddens,
                          const float* __restrict__ Wp,
                          const float* __restrict__ bp,
                          float* __restrict__ p) {
    int row  = blockIdx.x;
    int lane = threadIdx.x;   // 64 lanes
    const float* h = hiddens + (size_t)row * Hq;
    float a0 = 0.f, a1 = 0.f, a2 = 0.f;
    for (int i = lane; i < Hq; i += 64) {
        float hv = h[i];
        a0 += hv * Wp[i * 3 + 0];
        a1 += hv * Wp[i * 3 + 1];
        a2 += hv * Wp[i * 3 + 2];
    }
    for (int off = 32; off > 0; off >>= 1) {
        a0 += __shfl_down(a0, off);
        a1 += __shfl_down(a1, off);
        a2 += __shfl_down(a2, off);
    }
    if (lane == 0) {
        float l0 = a0 + bp[0], l1 = a1 + bp[1], l2 = a2 + bp[2];
        float M  = fmaxf(l0, fmaxf(l1, l2));
        float e0 = expf(l0 - M), e1 = expf(l1 - M), e2 = expf(l2 - M);
        float inv = 1.f / (e0 + e1 + e2);
        p[row * 3 + 0] = e0 * inv;
        p[row * 3 + 1] = e1 * inv;
        p[row * 3 + 2] = e2 * inv;
    }
}

// -------------------------------------------------------------------------
// K2: extract one-hot index per map row (argmax). One wave per row.
__global__ void extract_idx(const float* __restrict__ map, int ncols,
                            int* __restrict__ idx) {
    int row  = blockIdx.x;
    int lane = threadIdx.x;
    const float* r = map + (size_t)row * ncols;
    float best = -1.f; int bi = 0;
    for (int i = lane; i < ncols; i += 64) {
        float v = r[i];
        if (v > best) { best = v; bi = i; }
    }
    for (int off = 32; off > 0; off >>= 1) {
        float ob  = __shfl_down(best, off);
        int   obi = __shfl_down(bi, off);
        if (ob > best) { best = ob; bi = obi; }
    }
    if (lane == 0) idx[row] = bi;
}

// -------------------------------------------------------------------------
// Conversion: hiddens fp32 -> bf16 (same layout, k contiguous)
__global__ __launch_bounds__(256)
void convert_a(const float* __restrict__ in, __hip_bfloat16* __restrict__ o) {
    int i = blockIdx.x * 256 + threadIdx.x;
    float4 v = ((const float4*)in)[i];
    __hip_bfloat16* op = o + (size_t)i * 4;
    op[0] = __float2bfloat16(v.x);
    op[1] = __float2bfloat16(v.y);
    op[2] = __float2bfloat16(v.z);
    op[3] = __float2bfloat16(v.w);
}

// Transpose+convert: Wv (512 x 32000 fp32) -> Wt (32000 x 512 bf16)
__global__ __launch_bounds__(256)
void transpose_wv(const float* __restrict__ Wv, __hip_bfloat16* __restrict__ Wt) {
    __shared__ float t[32][33];
    int n0 = blockIdx.x * 32, k0 = blockIdx.y * 32;
    int tx = threadIdx.x, ty = threadIdx.y;   // 32 x 8
#pragma unroll
    for (int r = 0; r < 4; ++r)
        t[ty + r * 8][tx] = Wv[(size_t)(k0 + ty + r * 8) * Vq + n0 + tx];
    __syncthreads();
#pragma unroll
    for (int r = 0; r < 4; ++r)
        Wt[(size_t)(n0 + ty + r * 8) * Hq + k0 + tx] =
            __float2bfloat16(t[tx][ty + r * 8]);
}

// -------------------------------------------------------------------------
// K3: bf16 MFMA GEMM, register-staged depth-2 pipeline, 64B-coalesced
// staging loads, XOR-swizzled LDS, epilogue-fused per-block softmax stats.
// 128x128 tile, BK=32, 4 waves of 64x64 (4x4 x mfma 16x16x32).
// LDS layout: row-major [row(128)][kc(4, swizzled by row&3)][8 bf16].
__global__ __launch_bounds__(256)
void gemm_mfma(const unsigned short* __restrict__ A,
               const unsigned short* __restrict__ Bt,
               const float* __restrict__ bv,
               float* __restrict__ out,
               float* __restrict__ pm, float* __restrict__ pl,
               int* __restrict__ pc) {
    __shared__ __align__(16) unsigned short As[4096];   // 8 KB
    __shared__ __align__(16) unsigned short Bs[4096];   // 8 KB
    const int tid  = threadIdx.x;
    const int wave = tid >> 6, lane = tid & 63;
    const int bnIdx = blockIdx.y;
    const int bm = blockIdx.x * 128;
    const int bn = bnIdx * 128;
    const int wr = wave >> 1, wc = wave & 1;
    const int lr = lane & 15, kq = lane >> 4;

    // staging chunks: c in [0,512): row=c>>2, kc=c&3 (16B each). Thread owns
    // c0=tid, c1=tid+256 -> consecutive lanes read contiguous 64B runs.
    const int c0 = tid, c1 = tid + 256;
    const size_t gA0 = (size_t)(bm + (c0 >> 2)) * Hq + (c0 & 3) * 8;
    const size_t gA1 = (size_t)(bm + (c1 >> 2)) * Hq + (c1 & 3) * 8;
    const size_t gB0 = (size_t)(bn + (c0 >> 2)) * Hq + (c0 & 3) * 8;
    const size_t gB1 = (size_t)(bn + (c1 >> 2)) * Hq + (c1 & 3) * 8;
    const int lA0 = (c0 >> 2) * 32 + (((c0 & 3) ^ ((c0 >> 2) & 3)) * 8);
    const int lA1 = (c1 >> 2) * 32 + (((c1 & 3) ^ ((c1 >> 2) & 3)) * 8);

    fx4 acc[4][4];
#pragma unroll
    for (int i = 0; i < 4; ++i)
#pragma unroll
        for (int j = 0; j < 4; ++j)
            acc[i][j] = (fx4){0.f, 0.f, 0.f, 0.f};

    // depth-2 register pipeline
    uint4 sa[2][2], sb[2][2];
    sa[0][0] = *(const uint4*)(A + gA0);
    sa[0][1] = *(const uint4*)(A + gA1);
    sb[0][0] = *(const uint4*)(Bt + gB0);
    sb[0][1] = *(const uint4*)(Bt + gB1);
    sa[1][0] = *(const uint4*)(A + gA0 + 32);
    sa[1][1] = *(const uint4*)(A + gA1 + 32);
    sb[1][0] = *(const uint4*)(Bt + gB0 + 32);
    sb[1][1] = *(const uint4*)(Bt + gB1 + 32);

    const int permB = (kq ^ (lr & 3)) * 8;   // swizzled kc slot, in ushorts

#pragma unroll
    for (int it = 0; it < 16; ++it) {
        const int st = it & 1;
        __syncthreads();                       // LDS consumers of prev iter done
        *(uint4*)&As[lA0] = sa[st][0];
        *(uint4*)&As[lA1] = sa[st][1];
        *(uint4*)&Bs[lA0] = sb[st][0];
        *(uint4*)&Bs[lA1] = sb[st][1];
        __syncthreads();                       // LDS tile visible
        const int kn = (it + 2) * 32;          // prefetch 2 iters ahead
        if (kn < Hq) {
            sa[st][0] = *(const uint4*)(A + gA0 + kn);
            sa[st][1] = *(const uint4*)(A + gA1 + kn);
            sb[st][0] = *(const uint4*)(Bt + gB0 + kn);
            sb[st][1] = *(const uint4*)(Bt + gB1 + kn);
        }
        bf16x8 af[4], bfr[4];
#pragma unroll
        for (int i = 0; i < 4; ++i)
            af[i] = *(const bf16x8*)&As[(wr * 64 + i * 16 + lr) * 32 + permB];
#pragma unroll
        for (int j = 0; j < 4; ++j)
            bfr[j] = *(const bf16x8*)&Bs[(wc * 64 + j * 16 + lr) * 32 + permB];
#pragma unroll
        for (int i = 0; i < 4; ++i)
#pragma unroll
            for (int j = 0; j < 4; ++j)
                acc[i][j] = __builtin_amdgcn_mfma_f32_16x16x32_bf16(
                    af[i], bfr[j], acc[i][j], 0, 0, 0);
    }

    // ---- epilogue: scores + fused per-row partial (max, sumexp, argmax) ----
    float bvv[4];
#pragma unroll
    for (int j = 0; j < 4; ++j)
        bvv[j] = bv[bn + wc * 64 + j * 16 + lr];

    __syncthreads();                  // done with tiles; reuse LDS for stats
    float* sM = (float*)As;           // [128][2]
    float* sL = sM + 256;             // [128][2]
    int*   sC = (int*)Bs;             // [128][2]

#pragma unroll
    for (int i = 0; i < 4; ++i) {
        int rbase = wr * 64 + i * 16 + kq * 4;
#pragma unroll
        for (int r = 0; r < 4; ++r) {
            int rloc = rbase + r;
            float v[4];
            float m = -INFINITY; int c = 0x7fffffff;
#pragma unroll
            for (int j = 0; j < 4; ++j) {
                int gc = bn + wc * 64 + j * 16 + lr;
                float x = acc[i][j][r] + bvv[j];
                if (gc == 0) x = -1e30f;
                v[j] = x;
                out[(size_t)(bm + rloc) * OUTW + gc] = x;
                if (x > m) { m = x; c = gc; }
            }
            // reduce (max, argmax) over the 16 lanes sharing this row
#pragma unroll
            for (int off = 1; off < 16; off <<= 1) {
                float om = __shfl_xor(m, off);
                int   oc = __shfl_xor(c, off);
                if (om > m || (om == m && oc < c)) { m = om; c = oc; }
            }
            float l = 0.f;
#pragma unroll
            for (int j = 0; j < 4; ++j) l += __expf(v[j] - m);
#pragma unroll
            for (int off = 1; off < 16; off <<= 1)
                l += __shfl_xor(l, off);
            if (lr == 0) {
                sM[rloc * 2 + wc] = m;
                sL[rloc * 2 + wc] = l;
                sC[rloc * 2 + wc] = c;
            }
        }
    }
    __syncthreads();
    if (tid < 128) {
        float m0 = sM[tid * 2], m1 = sM[tid * 2 + 1];
        float l0 = sL[tid * 2], l1 = sL[tid * 2 + 1];
        int   cc0 = sC[tid * 2], cc1 = sC[tid * 2 + 1];
        float M = fmaxf(m0, m1);
        float L = l0 * __expf(m0 - M) + l1 * __expf(m1 - M);
        int   C = (m1 > m0 || (m1 == m0 && cc1 < cc0)) ? cc1 : cc0;
        size_t o = (size_t)(bm + tid) * 256 + bnIdx;
        pm[o] = M; pl[o] = L; pc[o] = C;
    }
}

// -------------------------------------------------------------------------
// K4: per-row reduction of 250 partials -> rowM, rowScale, vocab candidate.
__global__ __launch_bounds__(256)
void row_stats(const float* __restrict__ pm, const float* __restrict__ pl,
               const int* __restrict__ pc, const float* __restrict__ p,
               float* __restrict__ rowM, float* __restrict__ rowScale,
               float* __restrict__ cval, int* __restrict__ cidx) {
    int wave = threadIdx.x >> 6, lane = threadIdx.x & 63;
    int row  = blockIdx.x * 4 + wave;
    const float* pmr = pm + (size_t)row * 256;
    const float* plr = pl + (size_t)row * 256;
    const int*   pcr = pc + (size_t)row * 256;
    float m[4], l[4]; int c[4];
#pragma unroll
    for (int t = 0; t < 4; ++t) {
        int i = lane + t * 64;
        if (i < NBLK) { m[t] = pmr[i]; l[t] = plr[i]; c[t] = pcr[i]; }
        else          { m[t] = -INFINITY; l[t] = 0.f; c[t] = 0x7fffffff; }
    }
    float M = m[0]; int C = c[0];
#pragma unroll
    for (int t = 1; t < 4; ++t)
        if (m[t] > M || (m[t] == M && c[t] < C)) { M = m[t]; C = c[t]; }
#pragma unroll
    for (int off = 1; off < 64; off <<= 1) {
        float om = __shfl_xor(M, off);
        int   oc = __shfl_xor(C, off);
        if (om > M || (om == M && oc < C)) { M = om; C = oc; }
    }
    float Lp = 0.f;
#pragma unroll
    for (int t = 0; t < 4; ++t) Lp += l[t] * __expf(m[t] - M);
#pragma unroll
    for (int off = 1; off < 64; off <<= 1) Lp += __shfl_xor(Lp, off);
    if (lane == 0) {
        float pgen  = p[row * 3 + 2];
        float scale = pgen / Lp;
        rowM[row] = M; rowScale[row] = scale;
        cval[row * 3] = scale;   // winning vocab prob = exp(M-M)*scale
        cidx[row * 3] = C;
    }
}

// -------------------------------------------------------------------------
// K5: finalize vocab region in place: out = exp(s - M) * scale. One sweep.
__global__ __launch_bounds__(256)
void finalize(float* __restrict__ out, const float* __restrict__ rowM,
              const float* __restrict__ rowScale) {
    int row = blockIdx.x;
    float M = rowM[row], s = rowScale[row];
    float4* rp = (float4*)(out + (size_t)row * OUTW);
    int half = blockIdx.y * 4000;   // 8000 float4 per row, 2 y-blocks
    for (int i = threadIdx.x + half; i < half + 4000; i += 256) {
        float4 v = rp[i];
        v.x = __expf(v.x - M) * s;
        v.y = __expf(v.y - M) * s;
        v.z = __expf(v.z - M) * s;
        v.w = __expf(v.w - M) * s;
        rp[i] = v;
    }
}

// -------------------------------------------------------------------------
// K6: scatter-add copy distribution + fused region argmax -> candidate slot.
__global__ __launch_bounds__(256)
void copy_scatter(const float* __restrict__ att, const int* __restrict__ idx,
                  const float* __restrict__ p, int pcol, int slot,
                  int natt, int nout, float* __restrict__ out, int out_off,
                  float* __restrict__ cval, int* __restrict__ cidx) {
    int row = blockIdx.x;       // b*T + t
    int b   = row >> 9;         // /512
    int tid = threadIdx.x;
    __shared__ float acc[TDVq];
    for (int i = tid; i < nout; i += 256) acc[i] = 0.f;
    __syncthreads();
    const float* arow = att + (size_t)row * natt;
    const int*   ib   = idx + b * natt;
    for (int s = tid; s < natt; s += 256) {
        atomicAdd(&acc[ib[s]], arow[s]);
    }
    __syncthreads();
    float pc = p[row * 3 + pcol];
    float* orow = out + (size_t)row * OUTW + out_off;
    float bm_ = -INFINITY; int bi = 0;
    for (int v = tid; v < nout; v += 256) {
        float val = acc[v] * pc;
        orow[v] = val;
        if (val > bm_) { bm_ = val; bi = v; }
    }
    __shared__ float bs[256];
    __shared__ int   is_[256];
    bs[tid] = bm_; is_[tid] = bi;
    __syncthreads();
    for (int s = 128; s > 0; s >>= 1) {
        if (tid < s) {
            float v2 = bs[tid + s]; int i2 = is_[tid + s];
            if (v2 > bs[tid] || (v2 == bs[tid] && i2 < is_[tid])) {
                bs[tid] = v2; is_[tid] = i2;
            }
        }
        __syncthreads();
    }
    if (tid == 0) { cval[row * 3 + slot] = bs[0]; cidx[row * 3 + slot] = out_off + is_[0]; }
}

// -------------------------------------------------------------------------
// K7: combine 3 per-region argmax candidates -> predictions (as float).
__global__ void combine_pred(const float* __restrict__ cval,
                             const int* __restrict__ cidx,
                             float* __restrict__ pred) {
    int r = blockIdx.x * 256 + threadIdx.x;
    if (r >= ROWS) return;
    float v = cval[r * 3]; int i = cidx[r * 3];
    if (cval[r * 3 + 1] > v) { v = cval[r * 3 + 1]; i = cidx[r * 3 + 1]; }
    if (cval[r * 3 + 2] > v) { v = cval[r * 3 + 2]; i = cidx[r * 3 + 2]; }
    pred[r] = (float)i;
}

// -------------------------------------------------------------------------
extern "C" void kernel_launch(void* const* d_in, const int* in_sizes, int n_in,
                              void* d_out, int out_size, void* d_ws, size_t ws_size,
                              hipStream_t stream) {
    const float* hiddens = (const float*)d_in[0];
    const float* Wp      = (const float*)d_in[1];
    const float* bp      = (const float*)d_in[2];
    const float* Wv      = (const float*)d_in[3];
    const float* bv      = (const float*)d_in[4];
    const float* src_att = (const float*)d_in[5];
    const float* src_map = (const float*)d_in[6];
    const float* tgt_att = (const float*)d_in[7];
    const float* tgt_map = (const float*)d_in[8];

    float* out  = (float*)d_out;
    float* pred = out + (size_t)ROWS * OUTW;

    // workspace layout (bytes)
    char* ws = (char*)d_ws;
    float* p_ws     = (float*)(ws);                 // 24 KB
    int*   sidx     = (int*)(ws + (24 << 10));      // 8 KB
    int*   tidx     = (int*)(ws + (32 << 10));      // 8 KB
    float* cval     = (float*)(ws + (40 << 10));    // 24 KB
    int*   cidx     = (int*)(ws + (64 << 10));      // 24 KB
    float* rowM     = (float*)(ws + (88 << 10));    // 8 KB
    float* rowScale = (float*)(ws + (96 << 10));    // 8 KB
    float* pm_ws    = (float*)(ws + (128 << 10));                 // 2 MB
    float* pl_ws    = (float*)(ws + (128 << 10) + (2 << 20));     // 2 MB
    int*   pc_ws    = (int*)  (ws + (128 << 10) + (4 << 20));     // 2 MB
    __hip_bfloat16* A_bf = (__hip_bfloat16*)(ws + (128 << 10) + (6 << 20)); // 2 MB
    __hip_bfloat16* Wt   = (__hip_bfloat16*)(ws + (128 << 10) + (8 << 20)); // 32.75 MB

    // conversions
    convert_a<<<ROWS * Hq / 4 / 256, 256, 0, stream>>>(hiddens, A_bf);
    {
        dim3 tg(Vq / 32, Hq / 32);   // (1000, 16)
        dim3 tb(32, 8);
        transpose_wv<<<tg, tb, 0, stream>>>(Wv, Wt);
    }

    // gate probabilities + one-hot indices
    compute_p<<<ROWS, 64, 0, stream>>>(hiddens, Wp, bp, p_ws);
    extract_idx<<<Bq * Sq, 64, 0, stream>>>(src_map, SDVq, sidx);
    extract_idx<<<Bq * Tq, 64, 0, stream>>>(tgt_map, TDVq, tidx);

    // scores GEMM (MFMA, pipelined) + fused softmax partials
    {
        dim3 gg(ROWS / 128, NBLK);   // (16, 250)
        gemm_mfma<<<gg, 256, 0, stream>>>((const unsigned short*)A_bf,
                                          (const unsigned short*)Wt, bv, out,
                                          pm_ws, pl_ws, pc_ws);
    }

    // per-row stats reduction, then single-sweep finalize
    row_stats<<<ROWS / 4, 256, 0, stream>>>(pm_ws, pl_ws, pc_ws, p_ws,
                                            rowM, rowScale, cval, cidx);
    {
        dim3 fg(ROWS, 2);
        finalize<<<fg, 256, 0, stream>>>(out, rowM, rowScale);
    }

    // copy distributions, fused region argmax
    copy_scatter<<<ROWS, 256, 0, stream>>>(src_att, sidx, p_ws, 0, 1, Sq, SDVq,
                                           out, Vq, cval, cidx);
    copy_scatter<<<ROWS, 256, 0, stream>>>(tgt_att, tidx, p_ws, 1, 2, TDVq, TDVq,
                                           out, Vq + SDVq, cval, cidx);

    // predictions
    combine_pred<<<(ROWS + 255) / 256, 256, 0, stream>>>(cval, cidx, pred);
}